// Round 1
// baseline (959.757 us; speedup 1.0000x reference)
//
#include <hip/hip_runtime.h>
#include <math.h>

#define N_NODES 50000
#define N_EDGES 800000
#define N_QE    100000
#define D       128

// ---- workspace layout (bytes) ----
static const size_t O_CNT = 0;                      // int[N]
static const size_t O_OFF = 256u * 1024;            // int[N+1]
static const size_t O_CUR = 512u * 1024;            // int[N]
static const size_t O_SRC = 768u * 1024;            // int[E] (3.2 MB)
static const size_t O_A   = 8u << 20;               // float[N*D]  25.6 MB
static const size_t O_B   = O_A + 25600000u;        // float[N*D]  25.6 MB
static const size_t O_Z   = O_B + 25600000u;        // float[NE*D] 51.2 MB
// total ~110.8 MB

// ---- CSR build ----
__global__ void k_count(const int* __restrict__ dst, int* __restrict__ cnt) {
    int e = blockIdx.x * 256 + threadIdx.x;
    if (e < N_EDGES) atomicAdd(&cnt[dst[e]], 1);
}

__global__ void k_scan(const int* __restrict__ cnt, int* __restrict__ off,
                       int* __restrict__ cur) {
    __shared__ int sums[1024];
    const int t = threadIdx.x;
    const int seg = (N_NODES + 1023) / 1024;      // 49
    int lo = t * seg;
    int hi = lo + seg; if (hi > N_NODES) hi = N_NODES;
    int s = 0;
    for (int i = lo; i < hi && i < N_NODES; ++i) s += cnt[i];
    sums[t] = s;
    __syncthreads();
    for (int o = 1; o < 1024; o <<= 1) {
        int v = (t >= o) ? sums[t - o] : 0;
        __syncthreads();
        sums[t] += v;
        __syncthreads();
    }
    int run = sums[t] - s;                        // exclusive prefix of this segment
    for (int i = lo; i < hi && i < N_NODES; ++i) {
        off[i] = run; cur[i] = run;
        run += cnt[i];
    }
    if (t == 0) off[N_NODES] = N_EDGES;
}

__global__ void k_scatter(const int* __restrict__ src, const int* __restrict__ dst,
                          int* __restrict__ cur, int* __restrict__ srcs) {
    int e = blockIdx.x * 256 + threadIdx.x;
    if (e < N_EDGES) {
        int p = atomicAdd(&cur[dst[e]], 1);
        srcs[p] = src[e];
    }
}

// ---- GEMM: Y[rows x 128] = X[rows x 128] @ W[128 x 128] (+bias, relu) ----
// 64 rows per block, all 128 cols; safe for in-place (X == Y): each block reads
// only its own 64 rows (clamp stays in-block) and writes only in the epilogue.
template<bool BIAS, bool RELU>
__global__ __launch_bounds__(256)
void k_gemm(const float* __restrict__ X, const float* __restrict__ W,
            const float* __restrict__ bias, float* __restrict__ Y, int rows)
{
    __shared__ float xs[64][68];      // [row][k-chunk], pad 64->68 (16B aligned, bank-safe)
    __shared__ float ws[64 * 128];    // [k][c]
    const int tid = threadIdx.x;
    const int tx = tid & 31;          // cols tx*4 .. tx*4+3
    const int ty = tid >> 5;          // rows ty*8 .. ty*8+7
    const int row0 = blockIdx.x * 64;
    float acc[8][4] = {};

    for (int kc = 0; kc < 2; ++kc) {
        const int kb = kc * 64;
        // stage X tile (64 rows x 64 k)
        #pragma unroll
        for (int it = 0; it < 4; ++it) {
            int f = it * 256 + tid;             // 0..1023
            int r = f >> 4, kq = f & 15;
            int gr = row0 + r; if (gr >= rows) gr = rows - 1;
            float4 v = *(const float4*)(X + (size_t)gr * D + kb + kq * 4);
            *(float4*)&xs[r][kq * 4] = v;
        }
        // stage W tile (64 k x 128 c)
        #pragma unroll
        for (int it = 0; it < 8; ++it) {
            int f = it * 256 + tid;             // 0..2047
            int k = f >> 5, cq = f & 31;
            *(float4*)&ws[k * 128 + cq * 4] =
                *(const float4*)(W + (size_t)(kb + k) * D + cq * 4);
        }
        __syncthreads();

        #pragma unroll 2
        for (int k4 = 0; k4 < 64; k4 += 4) {
            float4 wv[4];
            #pragma unroll
            for (int kk = 0; kk < 4; ++kk)
                wv[kk] = *(const float4*)&ws[(k4 + kk) * 128 + tx * 4];
            #pragma unroll
            for (int i = 0; i < 8; ++i) {
                float4 xv = *(const float4*)&xs[ty * 8 + i][k4];
                float xk[4] = {xv.x, xv.y, xv.z, xv.w};
                #pragma unroll
                for (int kk = 0; kk < 4; ++kk) {
                    acc[i][0] = fmaf(xk[kk], wv[kk].x, acc[i][0]);
                    acc[i][1] = fmaf(xk[kk], wv[kk].y, acc[i][1]);
                    acc[i][2] = fmaf(xk[kk], wv[kk].z, acc[i][2]);
                    acc[i][3] = fmaf(xk[kk], wv[kk].w, acc[i][3]);
                }
            }
        }
        __syncthreads();
    }

    #pragma unroll
    for (int i = 0; i < 8; ++i) {
        int gr = row0 + ty * 8 + i;
        if (gr < rows) {
            float4 o = make_float4(acc[i][0], acc[i][1], acc[i][2], acc[i][3]);
            if (BIAS) {
                o.x += bias[tx * 4 + 0]; o.y += bias[tx * 4 + 1];
                o.z += bias[tx * 4 + 2]; o.w += bias[tx * 4 + 3];
            }
            if (RELU) {
                o.x = fmaxf(o.x, 0.f); o.y = fmaxf(o.y, 0.f);
                o.z = fmaxf(o.z, 0.f); o.w = fmaxf(o.w, 0.f);
            }
            *(float4*)(Y + (size_t)gr * D + tx * 4) = o;
        }
    }
}

// ---- CSR aggregation: Hout[n] = (sum_{e: dst=n} Hin[src_e]) + bias, opt relu ----
template<bool RELU>
__global__ void k_agg(const float* __restrict__ Hin, const int* __restrict__ off,
                      const int* __restrict__ srcs, const float* __restrict__ bias,
                      float* __restrict__ Hout)
{
    const int tid = threadIdx.x;
    const int n = blockIdx.x * 2 + (tid >> 7);
    const int c = tid & 127;
    const int j0 = off[n], j1 = off[n + 1];
    float acc = 0.f;
    for (int j = j0; j < j1; ++j) {
        int s = srcs[j];
        acc += Hin[(size_t)s * D + c];
    }
    float v = acc + bias[c];
    if (RELU) v = fmaxf(v, 0.f);
    Hout[(size_t)n * D + c] = v;
}

// ---- Z0[e] = emb[s]*emb[d] (elementwise) ----
__global__ void k_z0(const float* __restrict__ emb, const int* __restrict__ te,
                     float* __restrict__ Z) {
    const int tid = threadIdx.x;
    const int e = blockIdx.x * 2 + (tid >> 7);
    const int c = tid & 127;
    const int s = te[e * 2], d = te[e * 2 + 1];
    Z[(size_t)e * D + c] = emb[(size_t)s * D + c] * emb[(size_t)d * D + c];
}

// ---- final: z @ P3 + pb3 -> L2 normalize -> log_softmax (2 classes) ----
__global__ void k_final(const float* __restrict__ Z, const float* __restrict__ P3,
                        const float* __restrict__ pb3, float* __restrict__ out) {
    const int tid = threadIdx.x;
    const int lane = tid & 63;
    const int e = blockIdx.x * 4 + (tid >> 6);
    const float* z = Z + (size_t)e * D;
    float za = z[lane], zb = z[lane + 64];
    float a0 = za * P3[lane * 2]     + zb * P3[(lane + 64) * 2];
    float a1 = za * P3[lane * 2 + 1] + zb * P3[(lane + 64) * 2 + 1];
    #pragma unroll
    for (int o = 32; o > 0; o >>= 1) {
        a0 += __shfl_down(a0, o);
        a1 += __shfl_down(a1, o);
    }
    if (lane == 0) {
        float v0 = a0 + pb3[0], v1 = a1 + pb3[1];
        float nrm = fmaxf(sqrtf(v0 * v0 + v1 * v1), 1e-12f);
        v0 /= nrm; v1 /= nrm;
        float m = fmaxf(v0, v1);
        float lse = m + logf(expf(v0 - m) + expf(v1 - m));
        out[e * 2]     = v0 - lse;
        out[e * 2 + 1] = v1 - lse;
    }
}

extern "C" void kernel_launch(void* const* d_in, const int* in_sizes, int n_in,
                              void* d_out, int out_size, void* d_ws, size_t ws_size,
                              hipStream_t stream)
{
    (void)in_sizes; (void)n_in; (void)out_size; (void)ws_size;
    const float* x   = (const float*)d_in[0];
    const int*   adj = (const int*)d_in[1];
    const int*   te  = (const int*)d_in[2];
    const float* W1  = (const float*)d_in[3];
    const float* b1  = (const float*)d_in[4];
    const float* W2  = (const float*)d_in[5];
    const float* b2  = (const float*)d_in[6];
    const float* W3  = (const float*)d_in[7];
    const float* b3  = (const float*)d_in[8];
    const float* P1  = (const float*)d_in[9];
    const float* pb1 = (const float*)d_in[10];
    const float* P2  = (const float*)d_in[11];
    const float* pb2 = (const float*)d_in[12];
    const float* P3  = (const float*)d_in[13];
    const float* pb3 = (const float*)d_in[14];
    float* out = (float*)d_out;

    char* ws = (char*)d_ws;
    int* cnt  = (int*)(ws + O_CNT);
    int* off  = (int*)(ws + O_OFF);
    int* cur  = (int*)(ws + O_CUR);
    int* srcs = (int*)(ws + O_SRC);
    float* A  = (float*)(ws + O_A);
    float* B  = (float*)(ws + O_B);
    float* Z  = (float*)(ws + O_Z);

    const int* esrc = adj;
    const int* edst = adj + N_EDGES;

    // CSR build (dst-sorted src list), reused by all 3 layers
    hipMemsetAsync(cnt, 0, N_NODES * sizeof(int), stream);
    k_count<<<N_EDGES / 256, 256, 0, stream>>>(edst, cnt);
    k_scan<<<1, 1024, 0, stream>>>(cnt, off, cur);
    k_scatter<<<N_EDGES / 256, 256, 0, stream>>>(esrc, edst, cur, srcs);

    const int gN = (N_NODES + 63) / 64;   // 782
    const int gQ = (N_QE + 63) / 64;      // 1563

    // GCN trunk: h = relu(agg(x@W) + b) x2, emb = agg(h@W3) + b3
    k_gemm<false, false><<<gN, 256, 0, stream>>>(x, W1, nullptr, A, N_NODES);
    k_agg<true><<<N_NODES / 2, 256, 0, stream>>>(A, off, srcs, b1, B);
    k_gemm<false, false><<<gN, 256, 0, stream>>>(B, W2, nullptr, B, N_NODES);
    k_agg<true><<<N_NODES / 2, 256, 0, stream>>>(B, off, srcs, b2, A);
    k_gemm<false, false><<<gN, 256, 0, stream>>>(A, W3, nullptr, A, N_NODES);
    k_agg<false><<<N_NODES / 2, 256, 0, stream>>>(A, off, srcs, b3, B); // B = emb

    // Link predictor
    k_z0<<<N_QE / 2, 256, 0, stream>>>(B, te, Z);
    k_gemm<true, true><<<gQ, 256, 0, stream>>>(Z, P1, pb1, Z, N_QE);
    k_gemm<true, true><<<gQ, 256, 0, stream>>>(Z, P2, pb2, Z, N_QE);
    k_final<<<N_QE / 4, 256, 0, stream>>>(Z, P3, pb3, out);
}

// Round 2
// 691.649 us; speedup vs baseline: 1.3876x; 1.3876x over previous
//
#include <hip/hip_runtime.h>
#include <math.h>

#define N_NODES 50000
#define N_EDGES 800000
#define N_QE    100000
#define D       128

// ---- workspace layout (bytes) ----
static const size_t O_CNT = 0;                      // int[N]
static const size_t O_OFF = 256u * 1024;            // int[N+1]
static const size_t O_CUR = 512u * 1024;            // int[N]
static const size_t O_SRC = 768u * 1024;            // int[E] (3.2 MB)
static const size_t O_A   = 8u << 20;               // float[N*D]  25.6 MB
static const size_t O_B   = O_A + 25600000u;        // float[N*D]  25.6 MB
static const size_t O_Z   = O_B + 25600000u;        // float[NE*D] 51.2 MB

// ---- CSR build ----
__global__ void k_count(const int* __restrict__ dst, int* __restrict__ cnt) {
    int e = blockIdx.x * 256 + threadIdx.x;
    if (e < N_EDGES) atomicAdd(&cnt[dst[e]], 1);
}

__global__ void k_scan(const int* __restrict__ cnt, int* __restrict__ off,
                       int* __restrict__ cur) {
    __shared__ int sums[1024];
    const int t = threadIdx.x;
    const int seg = (N_NODES + 1023) / 1024;      // 49
    int lo = t * seg;
    int hi = lo + seg; if (hi > N_NODES) hi = N_NODES;
    int s = 0;
    for (int i = lo; i < hi && i < N_NODES; ++i) s += cnt[i];
    sums[t] = s;
    __syncthreads();
    for (int o = 1; o < 1024; o <<= 1) {
        int v = (t >= o) ? sums[t - o] : 0;
        __syncthreads();
        sums[t] += v;
        __syncthreads();
    }
    int run = sums[t] - s;                        // exclusive prefix of this segment
    for (int i = lo; i < hi && i < N_NODES; ++i) {
        off[i] = run; cur[i] = run;
        run += cnt[i];
    }
    if (t == 0) off[N_NODES] = N_EDGES;
}

__global__ void k_scatter(const int* __restrict__ src, const int* __restrict__ dst,
                          int* __restrict__ cur, int* __restrict__ srcs) {
    int e = blockIdx.x * 256 + threadIdx.x;
    if (e < N_EDGES) {
        int p = atomicAdd(&cur[dst[e]], 1);
        srcs[p] = src[e];
    }
}

// ---- GEMM: Y[rows x 128] = X[rows x 128] @ W[128 x 128] (+bias, relu) ----
// 64 rows per block, all 128 cols; safe for in-place (X == Y): each block reads
// only its own 64 rows (clamp stays in-block) and writes only in the epilogue.
template<bool BIAS, bool RELU>
__global__ __launch_bounds__(256)
void k_gemm(const float* __restrict__ X, const float* __restrict__ W,
            const float* __restrict__ bias, float* __restrict__ Y, int rows)
{
    __shared__ float xs[64][68];      // [row][k-chunk], pad 64->68 (16B aligned, bank-safe)
    __shared__ float ws[64 * 128];    // [k][c]
    const int tid = threadIdx.x;
    const int tx = tid & 31;          // cols tx*4 .. tx*4+3
    const int ty = tid >> 5;          // rows ty*8 .. ty*8+7
    const int row0 = blockIdx.x * 64;
    float acc[8][4] = {};

    for (int kc = 0; kc < 2; ++kc) {
        const int kb = kc * 64;
        // stage X tile (64 rows x 64 k)
        #pragma unroll
        for (int it = 0; it < 4; ++it) {
            int f = it * 256 + tid;             // 0..1023
            int r = f >> 4, kq = f & 15;
            int gr = row0 + r; if (gr >= rows) gr = rows - 1;
            float4 v = *(const float4*)(X + (size_t)gr * D + kb + kq * 4);
            *(float4*)&xs[r][kq * 4] = v;
        }
        // stage W tile (64 k x 128 c)
        #pragma unroll
        for (int it = 0; it < 8; ++it) {
            int f = it * 256 + tid;             // 0..2047
            int k = f >> 5, cq = f & 31;
            *(float4*)&ws[k * 128 + cq * 4] =
                *(const float4*)(W + (size_t)(kb + k) * D + cq * 4);
        }
        __syncthreads();

        #pragma unroll 2
        for (int k4 = 0; k4 < 64; k4 += 4) {
            float4 wv[4];
            #pragma unroll
            for (int kk = 0; kk < 4; ++kk)
                wv[kk] = *(const float4*)&ws[(k4 + kk) * 128 + tx * 4];
            #pragma unroll
            for (int i = 0; i < 8; ++i) {
                float4 xv = *(const float4*)&xs[ty * 8 + i][k4];
                float xk[4] = {xv.x, xv.y, xv.z, xv.w};
                #pragma unroll
                for (int kk = 0; kk < 4; ++kk) {
                    acc[i][0] = fmaf(xk[kk], wv[kk].x, acc[i][0]);
                    acc[i][1] = fmaf(xk[kk], wv[kk].y, acc[i][1]);
                    acc[i][2] = fmaf(xk[kk], wv[kk].z, acc[i][2]);
                    acc[i][3] = fmaf(xk[kk], wv[kk].w, acc[i][3]);
                }
            }
        }
        __syncthreads();
    }

    #pragma unroll
    for (int i = 0; i < 8; ++i) {
        int gr = row0 + ty * 8 + i;
        if (gr < rows) {
            float4 o = make_float4(acc[i][0], acc[i][1], acc[i][2], acc[i][3]);
            if (BIAS) {
                o.x += bias[tx * 4 + 0]; o.y += bias[tx * 4 + 1];
                o.z += bias[tx * 4 + 2]; o.w += bias[tx * 4 + 3];
            }
            if (RELU) {
                o.x = fmaxf(o.x, 0.f); o.y = fmaxf(o.y, 0.f);
                o.z = fmaxf(o.z, 0.f); o.w = fmaxf(o.w, 0.f);
            }
            *(float4*)(Y + (size_t)gr * D + tx * 4) = o;
        }
    }
}

// ---- CSR aggregation: Hout[n] = (sum_{e: dst=n} Hin[src_e]) + bias, opt relu ----
// One wave per node. Lane = (half, quad): quad covers cols quad*4..+3 (float4),
// half selects which edge of a pair -> 2 edges x 512B = 1KB in flight per
// gather instruction. Src indices preloaded 64-at-a-time with one coalesced
// load, broadcast via shfl (no dependent scalar load on the gather path).
template<bool RELU>
__global__ __launch_bounds__(256)
void k_agg(const float* __restrict__ Hin, const int* __restrict__ off,
           const int* __restrict__ srcs, const float* __restrict__ bias,
           float* __restrict__ Hout)
{
    const int tid  = threadIdx.x;
    const int lane = tid & 63;
    const int n    = blockIdx.x * 4 + (tid >> 6);
    const int half = lane >> 5;
    const int q    = lane & 31;
    const int j0 = off[n], j1 = off[n + 1];

    float4 acc = make_float4(0.f, 0.f, 0.f, 0.f);
    int j = j0;
    while (j < j1) {
        int cnt = j1 - j; if (cnt > 64) cnt = 64;
        int idx = (lane < cnt) ? srcs[j + lane] : 0;
        #pragma unroll 4
        for (int k = half; k < cnt; k += 2) {
            int s = __shfl(idx, k, 64);
            const float4 v = *(const float4*)(Hin + (size_t)s * D + q * 4);
            acc.x += v.x; acc.y += v.y; acc.z += v.z; acc.w += v.w;
        }
        j += cnt;
    }
    acc.x += __shfl_xor(acc.x, 32, 64);
    acc.y += __shfl_xor(acc.y, 32, 64);
    acc.z += __shfl_xor(acc.z, 32, 64);
    acc.w += __shfl_xor(acc.w, 32, 64);
    if (half == 0) {
        const float4 bb = *(const float4*)(bias + q * 4);
        float4 o = make_float4(acc.x + bb.x, acc.y + bb.y,
                               acc.z + bb.z, acc.w + bb.w);
        if (RELU) {
            o.x = fmaxf(o.x, 0.f); o.y = fmaxf(o.y, 0.f);
            o.z = fmaxf(o.z, 0.f); o.w = fmaxf(o.w, 0.f);
        }
        *(float4*)(Hout + (size_t)n * D + q * 4) = o;
    }
}

// ---- Z0[e] = emb[s]*emb[d] (elementwise), float4 per lane ----
__global__ __launch_bounds__(256)
void k_z0(const float* __restrict__ emb, const int* __restrict__ te,
          float* __restrict__ Z) {
    const int t = blockIdx.x * 256 + threadIdx.x;
    const int e = t >> 5, q = t & 31;
    const int s = te[e * 2], d = te[e * 2 + 1];
    float4 a = *(const float4*)(emb + (size_t)s * D + q * 4);
    float4 b = *(const float4*)(emb + (size_t)d * D + q * 4);
    float4 o = make_float4(a.x * b.x, a.y * b.y, a.z * b.z, a.w * b.w);
    *(float4*)(Z + (size_t)e * D + q * 4) = o;
}

// ---- final: z @ P3 + pb3 -> L2 normalize -> log_softmax (2 classes) ----
__global__ void k_final(const float* __restrict__ Z, const float* __restrict__ P3,
                        const float* __restrict__ pb3, float* __restrict__ out) {
    const int tid = threadIdx.x;
    const int lane = tid & 63;
    const int e = blockIdx.x * 4 + (tid >> 6);
    const float* z = Z + (size_t)e * D;
    float za = z[lane], zb = z[lane + 64];
    float a0 = za * P3[lane * 2]     + zb * P3[(lane + 64) * 2];
    float a1 = za * P3[lane * 2 + 1] + zb * P3[(lane + 64) * 2 + 1];
    #pragma unroll
    for (int o = 32; o > 0; o >>= 1) {
        a0 += __shfl_down(a0, o);
        a1 += __shfl_down(a1, o);
    }
    if (lane == 0) {
        float v0 = a0 + pb3[0], v1 = a1 + pb3[1];
        float nrm = fmaxf(sqrtf(v0 * v0 + v1 * v1), 1e-12f);
        v0 /= nrm; v1 /= nrm;
        float m = fmaxf(v0, v1);
        float lse = m + logf(expf(v0 - m) + expf(v1 - m));
        out[e * 2]     = v0 - lse;
        out[e * 2 + 1] = v1 - lse;
    }
}

extern "C" void kernel_launch(void* const* d_in, const int* in_sizes, int n_in,
                              void* d_out, int out_size, void* d_ws, size_t ws_size,
                              hipStream_t stream)
{
    (void)in_sizes; (void)n_in; (void)out_size; (void)ws_size;
    const float* x   = (const float*)d_in[0];
    const int*   adj = (const int*)d_in[1];
    const int*   te  = (const int*)d_in[2];
    const float* W1  = (const float*)d_in[3];
    const float* b1  = (const float*)d_in[4];
    const float* W2  = (const float*)d_in[5];
    const float* b2  = (const float*)d_in[6];
    const float* W3  = (const float*)d_in[7];
    const float* b3  = (const float*)d_in[8];
    const float* P1  = (const float*)d_in[9];
    const float* pb1 = (const float*)d_in[10];
    const float* P2  = (const float*)d_in[11];
    const float* pb2 = (const float*)d_in[12];
    const float* P3  = (const float*)d_in[13];
    const float* pb3 = (const float*)d_in[14];
    float* out = (float*)d_out;

    char* ws = (char*)d_ws;
    int* cnt  = (int*)(ws + O_CNT);
    int* off  = (int*)(ws + O_OFF);
    int* cur  = (int*)(ws + O_CUR);
    int* srcs = (int*)(ws + O_SRC);
    float* A  = (float*)(ws + O_A);
    float* B  = (float*)(ws + O_B);
    float* Z  = (float*)(ws + O_Z);

    const int* esrc = adj;
    const int* edst = adj + N_EDGES;

    // CSR build (dst-sorted src list), reused by all 3 layers
    hipMemsetAsync(cnt, 0, N_NODES * sizeof(int), stream);
    k_count<<<N_EDGES / 256, 256, 0, stream>>>(edst, cnt);
    k_scan<<<1, 1024, 0, stream>>>(cnt, off, cur);
    k_scatter<<<N_EDGES / 256, 256, 0, stream>>>(esrc, edst, cur, srcs);

    const int gN = (N_NODES + 63) / 64;   // 782
    const int gQ = (N_QE + 63) / 64;      // 1563

    // GCN trunk: h = relu(agg(x@W) + b) x2, emb = agg(h@W3) + b3
    k_gemm<false, false><<<gN, 256, 0, stream>>>(x, W1, nullptr, A, N_NODES);
    k_agg<true><<<N_NODES / 4, 256, 0, stream>>>(A, off, srcs, b1, B);
    k_gemm<false, false><<<gN, 256, 0, stream>>>(B, W2, nullptr, B, N_NODES);
    k_agg<true><<<N_NODES / 4, 256, 0, stream>>>(B, off, srcs, b2, A);
    k_gemm<false, false><<<gN, 256, 0, stream>>>(A, W3, nullptr, A, N_NODES);
    k_agg<false><<<N_NODES / 4, 256, 0, stream>>>(A, off, srcs, b3, B); // B = emb

    // Link predictor
    k_z0<<<N_QE * 32 / 256, 256, 0, stream>>>(B, te, Z);
    k_gemm<true, true><<<gQ, 256, 0, stream>>>(Z, P1, pb1, Z, N_QE);
    k_gemm<true, true><<<gQ, 256, 0, stream>>>(Z, P2, pb2, Z, N_QE);
    k_final<<<N_QE / 4, 256, 0, stream>>>(Z, P3, pb3, out);
}

// Round 5
// 540.802 us; speedup vs baseline: 1.7747x; 1.2789x over previous
//
#include <hip/hip_runtime.h>
#include <math.h>

#define N_NODES 50000
#define N_EDGES 800000
#define N_QE    100000
#define D       128

// ---- workspace layout (bytes) ----
static const size_t O_CNT = 0;                        // int[N]
static const size_t O_OFF = 256u * 1024;              // int[N+1]
static const size_t O_CUR = 512u * 1024;              // int[N]
static const size_t O_BS  = 768u * 1024;              // int[256] block sums
static const size_t O_SRC = 1024u * 1024;             // int[E] (3.2 MB)
static const size_t O_A   = 8u << 20;                 // float[N*D] 25.6 MB
static const size_t O_B   = O_A + 25600000u;          // float[N*D] 25.6 MB

// ---- CSR build ----
__global__ void k_count(const int* __restrict__ dst, int* __restrict__ cnt) {
    int e = blockIdx.x * 256 + threadIdx.x;
    if (e < N_EDGES) atomicAdd(&cnt[dst[e]], 1);
}

__global__ __launch_bounds__(256)
void k_scan1(const int* __restrict__ cnt, int* __restrict__ off,
             int* __restrict__ bsum) {
    __shared__ int sh[256];
    const int t = threadIdx.x;
    const int i = blockIdx.x * 256 + t;
    int v = (i < N_NODES) ? cnt[i] : 0;
    sh[t] = v;
    __syncthreads();
    #pragma unroll
    for (int o = 1; o < 256; o <<= 1) {
        int u = (t >= o) ? sh[t - o] : 0;
        __syncthreads();
        sh[t] += u;
        __syncthreads();
    }
    if (i < N_NODES) off[i] = sh[t] - v;
    if (t == 255) bsum[blockIdx.x] = sh[255];
}

__global__ __launch_bounds__(256)
void k_scan2(int* __restrict__ bsum, int nblk) {
    __shared__ int sh[256];
    const int t = threadIdx.x;
    int v = (t < nblk) ? bsum[t] : 0;
    sh[t] = v;
    __syncthreads();
    #pragma unroll
    for (int o = 1; o < 256; o <<= 1) {
        int u = (t >= o) ? sh[t - o] : 0;
        __syncthreads();
        sh[t] += u;
        __syncthreads();
    }
    if (t < nblk) bsum[t] = sh[t] - v;
}

__global__ __launch_bounds__(256)
void k_scan3(int* __restrict__ off, const int* __restrict__ bsum,
             int* __restrict__ cur) {
    const int i = blockIdx.x * 256 + threadIdx.x;
    if (i < N_NODES) {
        int o = off[i] + bsum[blockIdx.x];
        off[i] = o;
        cur[i] = o;
    }
    if (i == 0) off[N_NODES] = N_EDGES;
}

__global__ void k_scatter(const int* __restrict__ src, const int* __restrict__ dst,
                          int* __restrict__ cur, int* __restrict__ srcs) {
    int e = blockIdx.x * 256 + threadIdx.x;
    if (e < N_EDGES) {
        int p = atomicAdd(&cur[dst[e]], 1);
        srcs[p] = src[e];
    }
}

// ---- GEMM: Y[rows x 128] = X[rows x 128] @ W[128 x 128], fp32 ----
// In-place safe (X==Y): block reads only its own 64 rows (clamp stays
// in-block), writes only in epilogue.
__global__ __launch_bounds__(256)
void k_gemm(const float* __restrict__ X, const float* __restrict__ W,
            float* __restrict__ Y, int rows)
{
    __shared__ float xs[64][68];
    __shared__ float ws[64 * 128];
    const int tid = threadIdx.x;
    const int tx = tid & 31;
    const int ty = tid >> 5;
    const int row0 = blockIdx.x * 64;
    float acc[8][4] = {};

    for (int kc = 0; kc < 2; ++kc) {
        const int kb = kc * 64;
        #pragma unroll
        for (int it = 0; it < 4; ++it) {
            int f = it * 256 + tid;
            int r = f >> 4, kq = f & 15;
            int gr = row0 + r; if (gr >= rows) gr = rows - 1;
            float4 v = *(const float4*)(X + (size_t)gr * D + kb + kq * 4);
            *(float4*)&xs[r][kq * 4] = v;
        }
        #pragma unroll
        for (int it = 0; it < 8; ++it) {
            int f = it * 256 + tid;
            int k = f >> 5, cq = f & 31;
            *(float4*)&ws[k * 128 + cq * 4] =
                *(const float4*)(W + (size_t)(kb + k) * D + cq * 4);
        }
        __syncthreads();

        #pragma unroll 2
        for (int k4 = 0; k4 < 64; k4 += 4) {
            float4 wv[4];
            #pragma unroll
            for (int kk = 0; kk < 4; ++kk)
                wv[kk] = *(const float4*)&ws[(k4 + kk) * 128 + tx * 4];
            #pragma unroll
            for (int i = 0; i < 8; ++i) {
                float4 xv = *(const float4*)&xs[ty * 8 + i][k4];
                float xk[4] = {xv.x, xv.y, xv.z, xv.w};
                #pragma unroll
                for (int kk = 0; kk < 4; ++kk) {
                    acc[i][0] = fmaf(xk[kk], wv[kk].x, acc[i][0]);
                    acc[i][1] = fmaf(xk[kk], wv[kk].y, acc[i][1]);
                    acc[i][2] = fmaf(xk[kk], wv[kk].z, acc[i][2]);
                    acc[i][3] = fmaf(xk[kk], wv[kk].w, acc[i][3]);
                }
            }
        }
        __syncthreads();
    }

    #pragma unroll
    for (int i = 0; i < 8; ++i) {
        int gr = row0 + ty * 8 + i;
        if (gr < rows)
            *(float4*)(Y + (size_t)gr * D + tx * 4) =
                make_float4(acc[i][0], acc[i][1], acc[i][2], acc[i][3]);
    }
}

// ---- CSR aggregation (fp32): Hout[n] = sum Hin[src] + bias, opt relu ----
// One wave per node; lane=(half,q): 2 edges x 512B in flight per gather
// instruction; indices preloaded coalesced + shfl broadcast.
template<bool RELU>
__global__ __launch_bounds__(256)
void k_agg(const float* __restrict__ Hin, const int* __restrict__ off,
           const int* __restrict__ srcs, const float* __restrict__ bias,
           float* __restrict__ Hout)
{
    const int tid  = threadIdx.x;
    const int lane = tid & 63;
    const int n    = blockIdx.x * 4 + (tid >> 6);
    const int half = lane >> 5;
    const int q    = lane & 31;
    const int j0 = off[n], j1 = off[n + 1];

    float4 acc = make_float4(0.f, 0.f, 0.f, 0.f);
    int j = j0;
    while (j < j1) {
        int cnt = j1 - j; if (cnt > 64) cnt = 64;
        int idx = (lane < cnt) ? srcs[j + lane] : 0;
        #pragma unroll 4
        for (int k = half; k < cnt; k += 2) {
            int s = __shfl(idx, k, 64);
            const float4 v = *(const float4*)(Hin + (size_t)s * D + q * 4);
            acc.x += v.x; acc.y += v.y; acc.z += v.z; acc.w += v.w;
        }
        j += cnt;
    }
    acc.x += __shfl_xor(acc.x, 32, 64);
    acc.y += __shfl_xor(acc.y, 32, 64);
    acc.z += __shfl_xor(acc.z, 32, 64);
    acc.w += __shfl_xor(acc.w, 32, 64);
    if (half == 0) {
        const float4 bb = *(const float4*)(bias + q * 4);
        float4 o = make_float4(acc.x + bb.x, acc.y + bb.y,
                               acc.z + bb.z, acc.w + bb.w);
        if (RELU) {
            o.x = fmaxf(o.x, 0.f); o.y = fmaxf(o.y, 0.f);
            o.z = fmaxf(o.z, 0.f); o.w = fmaxf(o.w, 0.f);
        }
        *(float4*)(Hout + (size_t)n * D + q * 4) = o;
    }
}

// ---- fused link predictor ----
// Per block: 64 edges. z = emb[s]*emb[d] gathered into LDS; two chained
// 128x128 GEMMs (weights staged 64-k at a time in LDS, acc in registers,
// relu + writeback to LDS between layers); P3 dot + normalize + log_softmax
// epilogue, reduced across the 32 lanes of each half-wave.
__global__ __launch_bounds__(256)
void k_pred(const float* __restrict__ emb, const int* __restrict__ te,
            const float* __restrict__ P1, const float* __restrict__ pb1,
            const float* __restrict__ P2, const float* __restrict__ pb2,
            const float* __restrict__ P3, const float* __restrict__ pb3,
            float* __restrict__ out)
{
    __shared__ float xs[64][136];     // full 128-k activations, +8 pad
    __shared__ float ws[64 * 128];    // one 64-k weight chunk
    const int tid = threadIdx.x;
    const int tx = tid & 31;
    const int ty = tid >> 5;
    const int row0 = blockIdx.x * 64;

    // stage z0 = emb[s] * emb[d]
    #pragma unroll
    for (int it = 0; it < 8; ++it) {
        int slot = it * 256 + tid;          // 0..2047
        int r = slot >> 5, c4 = slot & 31;
        int e = row0 + r; if (e >= N_QE) e = N_QE - 1;
        int s = te[e * 2], d = te[e * 2 + 1];
        float4 a = *(const float4*)(emb + (size_t)s * D + c4 * 4);
        float4 b = *(const float4*)(emb + (size_t)d * D + c4 * 4);
        *(float4*)&xs[r][c4 * 4] =
            make_float4(a.x * b.x, a.y * b.y, a.z * b.z, a.w * b.w);
    }

    float acc[8][4];

    #pragma unroll
    for (int layer = 0; layer < 2; ++layer) {
        const float* W = layer ? P2 : P1;
        const float* bb = layer ? pb2 : pb1;
        #pragma unroll
        for (int i = 0; i < 8; ++i)
            #pragma unroll
            for (int c = 0; c < 4; ++c) acc[i][c] = 0.f;

        for (int kc = 0; kc < 2; ++kc) {
            const int kb = kc * 64;
            __syncthreads();              // ws free of previous readers / xs ready
            #pragma unroll
            for (int it = 0; it < 8; ++it) {
                int f = it * 256 + tid;
                int k = f >> 5, cq = f & 31;
                *(float4*)&ws[k * 128 + cq * 4] =
                    *(const float4*)(W + (size_t)(kb + k) * D + cq * 4);
            }
            __syncthreads();

            #pragma unroll 2
            for (int k4 = 0; k4 < 64; k4 += 4) {
                float4 wv[4];
                #pragma unroll
                for (int kk = 0; kk < 4; ++kk)
                    wv[kk] = *(const float4*)&ws[(k4 + kk) * 128 + tx * 4];
                #pragma unroll
                for (int i = 0; i < 8; ++i) {
                    float4 xv = *(const float4*)&xs[ty * 8 + i][kb + k4];
                    float xk[4] = {xv.x, xv.y, xv.z, xv.w};
                    #pragma unroll
                    for (int kk = 0; kk < 4; ++kk) {
                        acc[i][0] = fmaf(xk[kk], wv[kk].x, acc[i][0]);
                        acc[i][1] = fmaf(xk[kk], wv[kk].y, acc[i][1]);
                        acc[i][2] = fmaf(xk[kk], wv[kk].z, acc[i][2]);
                        acc[i][3] = fmaf(xk[kk], wv[kk].w, acc[i][3]);
                    }
                }
            }
        }
        // bias + relu
        #pragma unroll
        for (int i = 0; i < 8; ++i) {
            acc[i][0] = fmaxf(acc[i][0] + bb[tx * 4 + 0], 0.f);
            acc[i][1] = fmaxf(acc[i][1] + bb[tx * 4 + 1], 0.f);
            acc[i][2] = fmaxf(acc[i][2] + bb[tx * 4 + 2], 0.f);
            acc[i][3] = fmaxf(acc[i][3] + bb[tx * 4 + 3], 0.f);
        }
        if (layer == 0) {
            __syncthreads();              // all xs reads of this layer done
            #pragma unroll
            for (int i = 0; i < 8; ++i)
                *(float4*)&xs[ty * 8 + i][tx * 4] =
                    make_float4(acc[i][0], acc[i][1], acc[i][2], acc[i][3]);
        }
    }

    // epilogue: v = z @ P3 + pb3 (2 cols), reduce over 32 lanes per half-wave
    float4 p3a = *(const float4*)(P3 + tx * 8);      // rows tx*4,tx*4+1
    float4 p3b = *(const float4*)(P3 + tx * 8 + 4);  // rows tx*4+2,tx*4+3
    const float q0 = pb3[0], q1 = pb3[1];
    #pragma unroll
    for (int i = 0; i < 8; ++i) {
        float p0 = acc[i][0] * p3a.x + acc[i][1] * p3a.z
                 + acc[i][2] * p3b.x + acc[i][3] * p3b.z;
        float p1 = acc[i][0] * p3a.y + acc[i][1] * p3a.w
                 + acc[i][2] * p3b.y + acc[i][3] * p3b.w;
        #pragma unroll
        for (int o = 1; o < 32; o <<= 1) {
            p0 += __shfl_xor(p0, o, 64);
            p1 += __shfl_xor(p1, o, 64);
        }
        if (tx == 0) {
            int gr = row0 + ty * 8 + i;
            if (gr < N_QE) {
                float v0 = p0 + q0, v1 = p1 + q1;
                float nrm = fmaxf(sqrtf(v0 * v0 + v1 * v1), 1e-12f);
                v0 /= nrm; v1 /= nrm;
                float m = fmaxf(v0, v1);
                float lse = m + logf(expf(v0 - m) + expf(v1 - m));
                out[gr * 2]     = v0 - lse;
                out[gr * 2 + 1] = v1 - lse;
            }
        }
    }
}

extern "C" void kernel_launch(void* const* d_in, const int* in_sizes, int n_in,
                              void* d_out, int out_size, void* d_ws, size_t ws_size,
                              hipStream_t stream)
{
    (void)in_sizes; (void)n_in; (void)out_size; (void)ws_size;
    const float* x   = (const float*)d_in[0];
    const int*   adj = (const int*)d_in[1];
    const int*   te  = (const int*)d_in[2];
    const float* W1  = (const float*)d_in[3];
    const float* b1  = (const float*)d_in[4];
    const float* W2  = (const float*)d_in[5];
    const float* b2  = (const float*)d_in[6];
    const float* W3  = (const float*)d_in[7];
    const float* b3  = (const float*)d_in[8];
    const float* P1  = (const float*)d_in[9];
    const float* pb1 = (const float*)d_in[10];
    const float* P2  = (const float*)d_in[11];
    const float* pb2 = (const float*)d_in[12];
    const float* P3  = (const float*)d_in[13];
    const float* pb3 = (const float*)d_in[14];
    float* out = (float*)d_out;

    char* ws = (char*)d_ws;
    int* cnt  = (int*)(ws + O_CNT);
    int* off  = (int*)(ws + O_OFF);
    int* cur  = (int*)(ws + O_CUR);
    int* bsum = (int*)(ws + O_BS);
    int* srcs = (int*)(ws + O_SRC);
    float* A  = (float*)(ws + O_A);
    float* B  = (float*)(ws + O_B);

    const int* esrc = adj;
    const int* edst = adj + N_EDGES;

    const int SBLK = (N_NODES + 255) / 256;   // 196

    // CSR build (dst-sorted src list), reused by all 3 layers
    hipMemsetAsync(cnt, 0, N_NODES * sizeof(int), stream);
    k_count<<<N_EDGES / 256, 256, 0, stream>>>(edst, cnt);
    k_scan1<<<SBLK, 256, 0, stream>>>(cnt, off, bsum);
    k_scan2<<<1, 256, 0, stream>>>(bsum, SBLK);
    k_scan3<<<SBLK, 256, 0, stream>>>(off, bsum, cur);
    k_scatter<<<N_EDGES / 256, 256, 0, stream>>>(esrc, edst, cur, srcs);

    const int gN = (N_NODES + 63) / 64;   // 782
    const int gQ = (N_QE + 63) / 64;      // 1563

    // GCN trunk (all fp32)
    k_gemm<<<gN, 256, 0, stream>>>(x, W1, A, N_NODES);
    k_agg<true><<<N_NODES / 4, 256, 0, stream>>>(A, off, srcs, b1, B);
    k_gemm<<<gN, 256, 0, stream>>>(B, W2, B, N_NODES);
    k_agg<true><<<N_NODES / 4, 256, 0, stream>>>(B, off, srcs, b2, A);
    k_gemm<<<gN, 256, 0, stream>>>(A, W3, A, N_NODES);
    k_agg<false><<<N_NODES / 4, 256, 0, stream>>>(A, off, srcs, b3, B); // B = emb

    // fused link predictor
    k_pred<<<gQ, 256, 0, stream>>>(B, te, P1, pb1, P2, pb2, P3, pb3, out);
}